// Round 5
// baseline (2057.205 us; speedup 1.0000x reference)
//
#include <hip/hip_runtime.h>

#define BATCH 8
#define SEQ   4096
#define DIM   512

typedef __attribute__((ext_vector_type(8))) short bf16x8;
typedef __attribute__((ext_vector_type(4))) float f32x4;

__device__ __forceinline__ unsigned short f2bf(float f) {
  unsigned int u = __float_as_uint(f);
  unsigned int r = (u + 0x7fffu + ((u >> 16) & 1u)) >> 16;
  return (unsigned short)r;
}
__device__ __forceinline__ float bf2f(unsigned short s) {
  return __uint_as_float(((unsigned int)s) << 16);
}

// async global->LDS, 16B per lane; LDS dest = wave-uniform base + lane*16
__device__ __forceinline__ void gload_lds16(const void* g, void* l) {
  __builtin_amdgcn_global_load_lds(
      (const __attribute__((address_space(1))) unsigned int*)g,
      (__attribute__((address_space(3))) unsigned int*)l, 16, 0, 0);
}

// ---------------------------------------------------------------------------
// Transpose + split weights: Wt[e][d] = W[d][e] (* scale for rotation).
// ---------------------------------------------------------------------------
__global__ __launch_bounds__(256) void wt_split_kernel(
    const float* __restrict__ rot, const float* __restrict__ ent,
    unsigned short* __restrict__ wrh, unsigned short* __restrict__ wrl,
    unsigned short* __restrict__ weh, unsigned short* __restrict__ wel) {
  const float scale = 0.04419417382415922f;  // 1/sqrt(512)
  int g = blockIdx.x * 256 + threadIdx.x;
  for (int idx = g; idx < 512 * 512; idx += 128 * 256) {
    int d = idx >> 9, e = idx & 511;
    size_t o = (size_t)e * 512 + d;
    float v = rot[idx] * scale;
    unsigned short h = f2bf(v);
    wrh[o] = h; wrl[o] = f2bf(v - bf2f(h));
    float v2 = ent[idx];
    unsigned short h2 = f2bf(v2);
    weh[o] = h2; wel[o] = f2bf(v2 - bf2f(h2));
  }
}

// ---------------------------------------------------------------------------
// Transpose x: Xt[b][d][n] = x[b][n][d], bf16 hi only (PV is single-term).
// Also emits row-major bf16 split Xh/Xl (consumed by proj_both).
// ---------------------------------------------------------------------------
__global__ __launch_bounds__(256) void xt_split_kernel(
    const float* __restrict__ X, unsigned short* __restrict__ Th,
    unsigned short* __restrict__ Xh, unsigned short* __restrict__ Xl) {
  __shared__ float T[64][65];
  const int b = blockIdx.z, n0 = blockIdx.x * 64, d0 = blockIdx.y * 64;
  const int tid = threadIdx.x;
  for (int idx = tid; idx < 4096; idx += 256) {
    int r = idx >> 6, c = idx & 63;
    size_t gi = ((size_t)(b * SEQ + n0 + r)) * DIM + d0 + c;
    float v = X[gi];
    T[r][c] = v;
    unsigned short h = f2bf(v);
    Xh[gi] = h;
    Xl[gi] = f2bf(v - bf2f(h));
  }
  __syncthreads();
  for (int idx = tid; idx < 4096; idx += 256) {
    int r = idx >> 6, c = idx & 63;  // r: d, c: n
    size_t o = ((size_t)(b * DIM + d0 + r)) * SEQ + n0 + c;
    Th[o] = f2bf(T[c][r]);
  }
}

// ---------------------------------------------------------------------------
// Fused projection: Q = X@rot*scale, K = X@ent via bf16-split MFMA (3 terms).
// ---------------------------------------------------------------------------
__global__ __launch_bounds__(256, 2) void proj_both(
    const unsigned short* __restrict__ Xh, const unsigned short* __restrict__ Xl,
    const unsigned short* __restrict__ wrh, const unsigned short* __restrict__ wrl,
    const unsigned short* __restrict__ weh, const unsigned short* __restrict__ wel,
    unsigned short* __restrict__ qh, unsigned short* __restrict__ ql,
    unsigned short* __restrict__ kh, unsigned short* __restrict__ kl) {
  const int tid = threadIdx.x;
  const int w = tid >> 6, lane = tid & 63, l15 = lane & 15, quad = lane >> 4;
  const int rowBase = blockIdx.x * 64 + (w & 1) * 32;
  const int colBase = blockIdx.y * 64 + (w >> 1) * 32;
  f32x4 qa[2][2] = {}, ka[2][2] = {};
  const unsigned short *xph[2], *xpl[2];
  const unsigned short *rh[2], *rl[2], *eh[2], *el[2];
#pragma unroll
  for (int mi = 0; mi < 2; ++mi) {
    size_t o = (size_t)(rowBase + mi * 16 + l15) * DIM + quad * 8;
    xph[mi] = Xh + o; xpl[mi] = Xl + o;
  }
#pragma unroll
  for (int ni = 0; ni < 2; ++ni) {
    size_t o = (size_t)(colBase + ni * 16 + l15) * DIM + quad * 8;
    rh[ni] = wrh + o; rl[ni] = wrl + o; eh[ni] = weh + o; el[ni] = wel + o;
  }
  for (int d0 = 0; d0 < DIM; d0 += 32) {
    bf16x8 ah[2], al[2];
#pragma unroll
    for (int mi = 0; mi < 2; ++mi) {
      ah[mi] = *(const bf16x8*)(xph[mi] + d0);
      al[mi] = *(const bf16x8*)(xpl[mi] + d0);
    }
#pragma unroll
    for (int ni = 0; ni < 2; ++ni) {
      bf16x8 bh = *(const bf16x8*)(rh[ni] + d0);
      bf16x8 bl = *(const bf16x8*)(rl[ni] + d0);
      bf16x8 ch = *(const bf16x8*)(eh[ni] + d0);
      bf16x8 cl = *(const bf16x8*)(el[ni] + d0);
#pragma unroll
      for (int mi = 0; mi < 2; ++mi) {
        qa[mi][ni] = __builtin_amdgcn_mfma_f32_16x16x32_bf16(ah[mi], bh, qa[mi][ni], 0, 0, 0);
        qa[mi][ni] = __builtin_amdgcn_mfma_f32_16x16x32_bf16(ah[mi], bl, qa[mi][ni], 0, 0, 0);
        qa[mi][ni] = __builtin_amdgcn_mfma_f32_16x16x32_bf16(al[mi], bh, qa[mi][ni], 0, 0, 0);
        ka[mi][ni] = __builtin_amdgcn_mfma_f32_16x16x32_bf16(ah[mi], ch, ka[mi][ni], 0, 0, 0);
        ka[mi][ni] = __builtin_amdgcn_mfma_f32_16x16x32_bf16(ah[mi], cl, ka[mi][ni], 0, 0, 0);
        ka[mi][ni] = __builtin_amdgcn_mfma_f32_16x16x32_bf16(al[mi], ch, ka[mi][ni], 0, 0, 0);
      }
    }
  }
#pragma unroll
  for (int mi = 0; mi < 2; ++mi)
#pragma unroll
    for (int ni = 0; ni < 2; ++ni)
#pragma unroll
      for (int r = 0; r < 4; ++r) {
        int row = rowBase + mi * 16 + quad * 4 + r;
        int col = colBase + ni * 16 + l15;
        size_t o = (size_t)row * DIM + col;
        float v = qa[mi][ni][r];
        unsigned short h = f2bf(v);
        qh[o] = h; ql[o] = f2bf(v - bf2f(h));
        float v2 = ka[mi][ni][r];
        unsigned short h2 = f2bf(v2);
        kh[o] = h2; kl[o] = f2bf(v2 - bf2f(h2));
      }
}

// ---------------------------------------------------------------------------
// Flash attention, 8 waves (512 thr), 1 block/CU, BQ=32, BK=256.
//   - Q (hi+lo) pinned in LDS ONCE per block (64 KB, row-XOR-swizzled),
//     staged via global_load_lds; read-only thereafter -> no Q re-fetch,
//     no Q barriers, no Q register arrays (the r4 spill).
//   - K split 8-ways across waves (wave w owns cols w*32..w*32+31): no
//     cross-wave sharing -> K skips LDS entirely, direct global->reg,
//     double-buffered one 32-d chunk ahead (static kb[c&1] indexing).
//     S-phase has ZERO barriers and ZERO staging.
//   - Softmax: every wave holds all 32 rows for its col-slice; combine via
//     red1/red2[32][8]; only 2 barriers per 256-k iteration. All waves
//     redundantly compute m/l -> no broadcast.
//   - PsH 32x256 bf16 (16 KB), 5-bit XOR block swizzle; PV per wave covers
//     d-slice w*64 (Of = 32 regs). Next-iter chunk-0 K prefetch issued at
//     c=15 -> covered by softmax+PV.
//   - LDS = 82 KB -> 1 block/CU, 2 waves/SIMD co-scheduled (same block).
// ---------------------------------------------------------------------------
#define LOADK(BUF, KROW0, CC)                                                  \
  do {                                                                         \
    _Pragma("unroll") for (int s_ = 0; s_ < 2; ++s_) {                         \
      const size_t ro_ =                                                       \
          (size_t)((KROW0) + w * 32 + s_ * 16 + l15) * DIM + (CC)*32 + quad * 8; \
      kb[BUF][s_][0] = *(const bf16x8*)(kpl0 + ro_);                           \
      kb[BUF][s_][1] = *(const bf16x8*)(kpl1 + ro_);                           \
    }                                                                          \
  } while (0)

__global__ __launch_bounds__(512, 2) void attn_mfma(
    const unsigned short* __restrict__ Qh, const unsigned short* __restrict__ Ql,
    const unsigned short* __restrict__ Kh, const unsigned short* __restrict__ Kl,
    const unsigned short* __restrict__ Xth, float* __restrict__ out,
    float* __restrict__ Opart, float* __restrict__ Mp, float* __restrict__ Lp) {
  __shared__ short Qpin[32768];          // 64 KB: [plane][32 rows][512 d], swz
  __shared__ unsigned short PsH[8192];   // 16 KB: [32 rows][256 cols], swz
  __shared__ float red1[32][8], red2[32][8];

  const int tid = threadIdx.x;
  const int w = tid >> 6, lane = tid & 63, l15 = lane & 15, quad = lane >> 4;
  const int b = blockIdx.x, q0 = blockIdx.y * 32;
  const int iters = (SEQ / 256) / gridDim.z;
  const int kbase = blockIdx.z * iters * 256;
  const int dbase = w * 64;  // PV output d-slice per wave

  // ---- one-time Q pin: LDS[row][P] holds Q[row][P ^ (row&7)] (16B blocks).
  // dest off (shorts) = j*4096 + w*512 + lane*8 -> plane j>>2, row (j&3)*8+w
  // (row&7 == w), phys block = lane -> src block = lane ^ w.
#pragma unroll
  for (int j = 0; j < 8; ++j) {
    const int row = (j & 3) * 8 + w;
    const unsigned short* src =
        ((j >> 2) ? Ql : Qh) + (size_t)(b * SEQ + q0 + row) * DIM + (lane ^ w) * 8;
    gload_lds16(src, &Qpin[j * 4096 + w * 512]);
  }
  __syncthreads();  // one-time: drains Q staging, all waves see full Qpin

  const unsigned short* kpl0 = Kh + (size_t)b * SEQ * DIM;
  const unsigned short* kpl1 = Kl + (size_t)b * SEQ * DIM;

  bf16x8 kb[2][2][2];  // [buf][k-subtile][plane], always statically indexed
  f32x4 Of[2][4] = {};
  float m_r[2][4], l_r[2][4];
#pragma unroll
  for (int qs = 0; qs < 2; ++qs)
#pragma unroll
    for (int r = 0; r < 4; ++r) { m_r[qs][r] = -3.0e38f; l_r[qs][r] = 0.0f; }

  LOADK(0, kbase, 0);  // prefetch chunk 0

  for (int t = 0; t < iters; ++t) {
    const int k0 = kbase + t * 256;
    f32x4 sa[2][2] = {};  // [q-subtile][k-subtile]

    // ---- S = Q K^T over 16 chunks of 32 d: barrier-free, reg-dbuf K ----
#pragma unroll
    for (int c = 0; c < 16; ++c) {
      if (c < 15) {
        LOADK((c + 1) & 1, k0, c + 1);
      } else if (t + 1 < iters) {
        LOADK(0, k0 + 256, 0);  // next iter chunk 0; lands during softmax+PV
      }
      bf16x8 qfh[2], qfl[2];
#pragma unroll
      for (int qs = 0; qs < 2; ++qs) {
        const int row = qs * 16 + l15;
        const int off = row * 512 + ((c * 4 + quad) ^ (l15 & 7)) * 8;
        qfh[qs] = *(const bf16x8*)&Qpin[off];
        qfl[qs] = *(const bf16x8*)&Qpin[16384 + off];
      }
      __builtin_amdgcn_s_setprio(1);
#pragma unroll
      for (int qs = 0; qs < 2; ++qs)
#pragma unroll
        for (int s = 0; s < 2; ++s) {
          sa[qs][s] = __builtin_amdgcn_mfma_f32_16x16x32_bf16(
              qfh[qs], kb[c & 1][s][0], sa[qs][s], 0, 0, 0);
          sa[qs][s] = __builtin_amdgcn_mfma_f32_16x16x32_bf16(
              qfh[qs], kb[c & 1][s][1], sa[qs][s], 0, 0, 0);
          sa[qs][s] = __builtin_amdgcn_mfma_f32_16x16x32_bf16(
              qfl[qs], kb[c & 1][s][0], sa[qs][s], 0, 0, 0);
        }
      __builtin_amdgcn_s_setprio(0);
    }

    // ---- online softmax: wave owns all 32 rows for cols [w*32, w*32+32) ----
#pragma unroll
    for (int qs = 0; qs < 2; ++qs)
#pragma unroll
      for (int r = 0; r < 4; ++r) {
        float v = fmaxf(sa[qs][0][r], sa[qs][1][r]);
#pragma unroll
        for (int off = 1; off < 16; off <<= 1) v = fmaxf(v, __shfl_xor(v, off, 64));
        if (l15 == 0) red1[qs * 16 + quad * 4 + r][w] = v;
      }
    asm volatile("s_waitcnt lgkmcnt(0)" ::: "memory");
    __builtin_amdgcn_sched_barrier(0);
    __builtin_amdgcn_s_barrier();  // B1

    float al_r[2][4];
#pragma unroll
    for (int qs = 0; qs < 2; ++qs)
#pragma unroll
      for (int r = 0; r < 4; ++r) {
        const int row = qs * 16 + quad * 4 + r;
        f32x4 ra = *(const f32x4*)&red1[row][0];
        f32x4 rb = *(const f32x4*)&red1[row][4];
        float mx = fmaxf(fmaxf(fmaxf(ra[0], ra[1]), fmaxf(ra[2], ra[3])),
                         fmaxf(fmaxf(rb[0], rb[1]), fmaxf(rb[2], rb[3])));
        float mn = fmaxf(m_r[qs][r], mx);
        al_r[qs][r] = __expf(m_r[qs][r] - mn);
        m_r[qs][r] = mn;
        float p0 = __expf(sa[qs][0][r] - mn);
        float p1 = __expf(sa[qs][1][r] - mn);
        const int c0 = w * 32 + l15, c1 = c0 + 16;
        PsH[row * 256 + ((c0 >> 3) ^ row) * 8 + (c0 & 7)] = f2bf(p0);
        PsH[row * 256 + ((c1 >> 3) ^ row) * 8 + (c1 & 7)] = f2bf(p1);
        float sum = p0 + p1;
#pragma unroll
        for (int off = 1; off < 16; off <<= 1) sum += __shfl_xor(sum, off, 64);
        if (l15 == 0) red2[row][w] = sum;
      }
    asm volatile("s_waitcnt lgkmcnt(0)" ::: "memory");
    __builtin_amdgcn_sched_barrier(0);
    __builtin_amdgcn_s_barrier();  // B2

#pragma unroll
    for (int qs = 0; qs < 2; ++qs)
#pragma unroll
      for (int r = 0; r < 4; ++r) {
        const int row = qs * 16 + quad * 4 + r;
        f32x4 ra = *(const f32x4*)&red2[row][0];
        f32x4 rb = *(const f32x4*)&red2[row][4];
        l_r[qs][r] = l_r[qs][r] * al_r[qs][r] +
                     (ra[0] + ra[1] + ra[2] + ra[3] + rb[0] + rb[1] + rb[2] + rb[3]);
      }

    // ---- O = O*alpha + P @ x ; wave d-slice [dbase, dbase+64) ----
#pragma unroll
    for (int qt = 0; qt < 2; ++qt)
#pragma unroll
      for (int nt = 0; nt < 4; ++nt)
#pragma unroll
        for (int r = 0; r < 4; ++r) Of[qt][nt][r] *= al_r[qt][r];

    const unsigned short* Xb =
        Xth + ((size_t)(b * DIM + dbase) + l15) * SEQ + k0 + quad * 8;
#pragma unroll
    for (int ks = 0; ks < 8; ++ks) {
      bf16x8 Ph[2];
#pragma unroll
      for (int qt = 0; qt < 2; ++qt) {
        const int prow = qt * 16 + l15;
        const int phys = (ks * 4 + quad) ^ prow;
        Ph[qt] = *(const bf16x8*)&PsH[prow * 256 + phys * 8];
      }
      bf16x8 xf[4];
#pragma unroll
      for (int i = 0; i < 4; ++i)
        xf[i] = *(const bf16x8*)(Xb + (size_t)(i * 16) * SEQ + ks * 32);
      __builtin_amdgcn_s_setprio(1);
#pragma unroll
      for (int i = 0; i < 4; ++i)
#pragma unroll
        for (int qt = 0; qt < 2; ++qt)
          Of[qt][i] = __builtin_amdgcn_mfma_f32_16x16x32_bf16(
              Ph[qt], xf[i], Of[qt][i], 0, 0, 0);
      __builtin_amdgcn_s_setprio(0);
    }
    // no barrier here: next iter's PsH/red writes are gated by B1/B2, which
    // every wave reaches only after finishing this PV (program order).
  }

  // ---- epilogue: each wave writes its own rows x d-slice; no LDS needed ----
  if (gridDim.z == 1) {
#pragma unroll
    for (int qt = 0; qt < 2; ++qt)
#pragma unroll
      for (int r = 0; r < 4; ++r) {
        const float inv = 1.0f / l_r[qt][r];
        const size_t ro =
            ((size_t)(b * SEQ + q0 + qt * 16 + quad * 4 + r)) * DIM + dbase;
#pragma unroll
        for (int i = 0; i < 4; ++i) out[ro + i * 16 + l15] = Of[qt][i][r] * inv;
      }
  } else {
    float* Ob = (blockIdx.z == 0) ? out : Opart;
#pragma unroll
    for (int qt = 0; qt < 2; ++qt)
#pragma unroll
      for (int r = 0; r < 4; ++r) {
        const size_t ro =
            ((size_t)(b * SEQ + q0 + qt * 16 + quad * 4 + r)) * DIM + dbase;
#pragma unroll
        for (int i = 0; i < 4; ++i) Ob[ro + i * 16 + l15] = Of[qt][i][r];
      }
    if (w == 0 && l15 == 0) {
      size_t ri = (size_t)blockIdx.z * (BATCH * SEQ) + (size_t)b * SEQ + q0;
#pragma unroll
      for (int qs = 0; qs < 2; ++qs)
#pragma unroll
        for (int r = 0; r < 4; ++r) {
          Mp[ri + qs * 16 + quad * 4 + r] = m_r[qs][r];
          Lp[ri + qs * 16 + quad * 4 + r] = l_r[qs][r];
        }
    }
  }
}

// ---------------------------------------------------------------------------
// Merge split-K partials: z=0 partial lives in `out`, z=1 in Opart.
// ---------------------------------------------------------------------------
__global__ __launch_bounds__(256) void merge_kernel(
    float* __restrict__ out, const float* __restrict__ Op,
    const float* __restrict__ Mp, const float* __restrict__ Lp) {
  const int NR = BATCH * SEQ;
  size_t e = ((size_t)blockIdx.x * 256 + threadIdx.x) * 4;
  int row = (int)(e >> 9);
  float m0 = Mp[row], m1 = Mp[NR + row];
  float l0 = Lp[row], l1 = Lp[NR + row];
  float m = fmaxf(m0, m1);
  float a0 = __expf(m0 - m), a1 = __expf(m1 - m);
  float inv = 1.0f / (a0 * l0 + a1 * l1);
  float4 o0 = *(const float4*)(out + e);
  float4 o1 = *(const float4*)(Op + e);
  float4 r;
  r.x = (a0 * o0.x + a1 * o1.x) * inv;
  r.y = (a0 * o0.y + a1 * o1.y) * inv;
  r.z = (a0 * o0.z + a1 * o1.z) * inv;
  r.w = (a0 * o0.w + a1 * o1.w) * inv;
  *(float4*)(out + e) = r;
}

// ---------------------------------------------------------------------------
extern "C" void kernel_launch(void* const* d_in, const int* in_sizes, int n_in,
                              void* d_out, int out_size, void* d_ws,
                              size_t ws_size, hipStream_t stream) {
  const float* x   = (const float*)d_in[0];
  const float* rot = (const float*)d_in[1];
  const float* ent = (const float*)d_in[2];
  float* out = (float*)d_out;

  const size_t NE = (size_t)BATCH * SEQ * DIM;  // 16,777,216
  unsigned short* qh  = (unsigned short*)d_ws;
  unsigned short* ql  = qh + NE;
  unsigned short* kh  = ql + NE;
  unsigned short* kl  = kh + NE;
  unsigned short* xth = kl + NE;
  unsigned short* xh  = xth + NE;
  unsigned short* xl  = xh + NE;
  unsigned short* wrh = xl + NE;
  unsigned short* wrl = wrh + 262144;
  unsigned short* weh = wrl + 262144;
  unsigned short* wel = weh + 262144;
  float* Opart = (float*)(wel + 262144);  // NE floats (z=1 partial)
  float* Mp    = Opart + NE;              // 2 * 32768
  float* Lp    = Mp + 2 * (BATCH * SEQ);

  const size_t need2 =
      (7 * NE + 4 * 262144) * sizeof(unsigned short) +
      (NE + 4 * (size_t)(BATCH * SEQ)) * sizeof(float);
  const int splits = (ws_size >= need2) ? 2 : 1;

  wt_split_kernel<<<128, 256, 0, stream>>>(rot, ent, wrh, wrl, weh, wel);
  xt_split_kernel<<<dim3(SEQ / 64, DIM / 64, BATCH), 256, 0, stream>>>(x, xth, xh, xl);
  proj_both<<<dim3(BATCH * SEQ / 64, DIM / 64), 256, 0, stream>>>(
      xh, xl, wrh, wrl, weh, wel, qh, ql, kh, kl);

  attn_mfma<<<dim3(BATCH, SEQ / 32, splits), 512, 0, stream>>>(
      qh, ql, kh, kl, xth, out, Opart, Mp, Lp);
  if (splits == 2) {
    merge_kernel<<<(unsigned)(NE / 1024), 256, 0, stream>>>(out, Opart, Mp, Lp);
  }
}

// Round 6
// 2009.594 us; speedup vs baseline: 1.0237x; 1.0237x over previous
//
#include <hip/hip_runtime.h>

#define BATCH 8
#define SEQ   4096
#define DIM   512

typedef __attribute__((ext_vector_type(8))) short bf16x8;
typedef __attribute__((ext_vector_type(4))) float f32x4;

__device__ __forceinline__ unsigned short f2bf(float f) {
  unsigned int u = __float_as_uint(f);
  unsigned int r = (u + 0x7fffu + ((u >> 16) & 1u)) >> 16;
  return (unsigned short)r;
}
__device__ __forceinline__ float bf2f(unsigned short s) {
  return __uint_as_float(((unsigned int)s) << 16);
}

// async global->LDS, 16B per lane; LDS dest = wave-uniform base + lane*16
__device__ __forceinline__ void gload_lds16(const void* g, void* l) {
  __builtin_amdgcn_global_load_lds(
      (const __attribute__((address_space(1))) unsigned int*)g,
      (__attribute__((address_space(3))) unsigned int*)l, 16, 0, 0);
}

// ---------------------------------------------------------------------------
// Transpose + split weights: Wt[e][d] = W[d][e] (* scale for rotation).
// ---------------------------------------------------------------------------
__global__ __launch_bounds__(256) void wt_split_kernel(
    const float* __restrict__ rot, const float* __restrict__ ent,
    unsigned short* __restrict__ wrh, unsigned short* __restrict__ wrl,
    unsigned short* __restrict__ weh, unsigned short* __restrict__ wel) {
  const float scale = 0.04419417382415922f;  // 1/sqrt(512)
  int g = blockIdx.x * 256 + threadIdx.x;
  for (int idx = g; idx < 512 * 512; idx += 128 * 256) {
    int d = idx >> 9, e = idx & 511;
    size_t o = (size_t)e * 512 + d;
    float v = rot[idx] * scale;
    unsigned short h = f2bf(v);
    wrh[o] = h; wrl[o] = f2bf(v - bf2f(h));
    float v2 = ent[idx];
    unsigned short h2 = f2bf(v2);
    weh[o] = h2; wel[o] = f2bf(v2 - bf2f(h2));
  }
}

// ---------------------------------------------------------------------------
// Transpose x: Xt[b][d][n] = x[b][n][d], bf16 hi only (PV is single-term).
// Also emits row-major bf16 split Xh/Xl (consumed by proj_both).
// ---------------------------------------------------------------------------
__global__ __launch_bounds__(256) void xt_split_kernel(
    const float* __restrict__ X, unsigned short* __restrict__ Th,
    unsigned short* __restrict__ Xh, unsigned short* __restrict__ Xl) {
  __shared__ float T[64][65];
  const int b = blockIdx.z, n0 = blockIdx.x * 64, d0 = blockIdx.y * 64;
  const int tid = threadIdx.x;
  for (int idx = tid; idx < 4096; idx += 256) {
    int r = idx >> 6, c = idx & 63;
    size_t gi = ((size_t)(b * SEQ + n0 + r)) * DIM + d0 + c;
    float v = X[gi];
    T[r][c] = v;
    unsigned short h = f2bf(v);
    Xh[gi] = h;
    Xl[gi] = f2bf(v - bf2f(h));
  }
  __syncthreads();
  for (int idx = tid; idx < 4096; idx += 256) {
    int r = idx >> 6, c = idx & 63;  // r: d, c: n
    size_t o = ((size_t)(b * DIM + d0 + r)) * SEQ + n0 + c;
    Th[o] = f2bf(T[c][r]);
  }
}

// ---------------------------------------------------------------------------
// Fused projection: Q = X@rot*scale, K = X@ent via bf16-split MFMA (3 terms).
// ---------------------------------------------------------------------------
__global__ __launch_bounds__(256, 2) void proj_both(
    const unsigned short* __restrict__ Xh, const unsigned short* __restrict__ Xl,
    const unsigned short* __restrict__ wrh, const unsigned short* __restrict__ wrl,
    const unsigned short* __restrict__ weh, const unsigned short* __restrict__ wel,
    unsigned short* __restrict__ qh, unsigned short* __restrict__ ql,
    unsigned short* __restrict__ kh, unsigned short* __restrict__ kl) {
  const int tid = threadIdx.x;
  const int w = tid >> 6, lane = tid & 63, l15 = lane & 15, quad = lane >> 4;
  const int rowBase = blockIdx.x * 64 + (w & 1) * 32;
  const int colBase = blockIdx.y * 64 + (w >> 1) * 32;
  f32x4 qa[2][2] = {}, ka[2][2] = {};
  const unsigned short *xph[2], *xpl[2];
  const unsigned short *rh[2], *rl[2], *eh[2], *el[2];
#pragma unroll
  for (int mi = 0; mi < 2; ++mi) {
    size_t o = (size_t)(rowBase + mi * 16 + l15) * DIM + quad * 8;
    xph[mi] = Xh + o; xpl[mi] = Xl + o;
  }
#pragma unroll
  for (int ni = 0; ni < 2; ++ni) {
    size_t o = (size_t)(colBase + ni * 16 + l15) * DIM + quad * 8;
    rh[ni] = wrh + o; rl[ni] = wrl + o; eh[ni] = weh + o; el[ni] = wel + o;
  }
  for (int d0 = 0; d0 < DIM; d0 += 32) {
    bf16x8 ah[2], al[2];
#pragma unroll
    for (int mi = 0; mi < 2; ++mi) {
      ah[mi] = *(const bf16x8*)(xph[mi] + d0);
      al[mi] = *(const bf16x8*)(xpl[mi] + d0);
    }
#pragma unroll
    for (int ni = 0; ni < 2; ++ni) {
      bf16x8 bh = *(const bf16x8*)(rh[ni] + d0);
      bf16x8 bl = *(const bf16x8*)(rl[ni] + d0);
      bf16x8 ch = *(const bf16x8*)(eh[ni] + d0);
      bf16x8 cl = *(const bf16x8*)(el[ni] + d0);
#pragma unroll
      for (int mi = 0; mi < 2; ++mi) {
        qa[mi][ni] = __builtin_amdgcn_mfma_f32_16x16x32_bf16(ah[mi], bh, qa[mi][ni], 0, 0, 0);
        qa[mi][ni] = __builtin_amdgcn_mfma_f32_16x16x32_bf16(ah[mi], bl, qa[mi][ni], 0, 0, 0);
        qa[mi][ni] = __builtin_amdgcn_mfma_f32_16x16x32_bf16(al[mi], bh, qa[mi][ni], 0, 0, 0);
        ka[mi][ni] = __builtin_amdgcn_mfma_f32_16x16x32_bf16(ah[mi], ch, ka[mi][ni], 0, 0, 0);
        ka[mi][ni] = __builtin_amdgcn_mfma_f32_16x16x32_bf16(ah[mi], cl, ka[mi][ni], 0, 0, 0);
        ka[mi][ni] = __builtin_amdgcn_mfma_f32_16x16x32_bf16(al[mi], ch, ka[mi][ni], 0, 0, 0);
      }
    }
  }
#pragma unroll
  for (int mi = 0; mi < 2; ++mi)
#pragma unroll
    for (int ni = 0; ni < 2; ++ni)
#pragma unroll
      for (int r = 0; r < 4; ++r) {
        int row = rowBase + mi * 16 + quad * 4 + r;
        int col = colBase + ni * 16 + l15;
        size_t o = (size_t)row * DIM + col;
        float v = qa[mi][ni][r];
        unsigned short h = f2bf(v);
        qh[o] = h; ql[o] = f2bf(v - bf2f(h));
        float v2 = ka[mi][ni][r];
        unsigned short h2 = f2bf(v2);
        kh[o] = h2; kl[o] = f2bf(v2 - bf2f(h2));
      }
}

// ---------------------------------------------------------------------------
// Flash attention, 8 waves (512 thr), 1 block/CU, BQ=32, BK=256.
//   Round-6 change: REGISTER PIPELINE DEPTH (the one thing constant across
//   all prior rounds was a 1-chunk prefetch distance < miss latency).
//   - K ring depth 4 (kb[4][..] = 64 VGPR): issue chunk c+3 at chunk c ->
//     prefetch distance ~3 chunks > HBM-miss latency. Cross-iter chunks get
//     the whole softmax+PV window to land.
//   - PV X-fragment double buffer (xfr[2][4]): group ks prefetches ks+1.
//   At 1 block/CU (LDS-capped), VGPRs up to 256 are occupancy-free; we spend
//   ~100 of the ~160 idle ones on the two rings.
// ---------------------------------------------------------------------------
#define LOADK(BUF, KROW0, CC)                                                  \
  do {                                                                         \
    _Pragma("unroll") for (int s_ = 0; s_ < 2; ++s_) {                         \
      const size_t ro_ =                                                       \
          (size_t)((KROW0) + w * 32 + s_ * 16 + l15) * DIM + (CC)*32 + quad * 8; \
      kb[BUF][s_][0] = *(const bf16x8*)(kpl0 + ro_);                           \
      kb[BUF][s_][1] = *(const bf16x8*)(kpl1 + ro_);                           \
    }                                                                          \
  } while (0)

__global__ __launch_bounds__(512, 2) void attn_mfma(
    const unsigned short* __restrict__ Qh, const unsigned short* __restrict__ Ql,
    const unsigned short* __restrict__ Kh, const unsigned short* __restrict__ Kl,
    const unsigned short* __restrict__ Xth, float* __restrict__ out,
    float* __restrict__ Opart, float* __restrict__ Mp, float* __restrict__ Lp) {
  __shared__ short Qpin[32768];          // 64 KB: [plane][32 rows][512 d], swz
  __shared__ unsigned short PsH[8192];   // 16 KB: [32 rows][256 cols], swz
  __shared__ float red1[32][8], red2[32][8];

  const int tid = threadIdx.x;
  const int w = tid >> 6, lane = tid & 63, l15 = lane & 15, quad = lane >> 4;
  const int b = blockIdx.x, q0 = blockIdx.y * 32;
  const int iters = (SEQ / 256) / gridDim.z;
  const int kbase = blockIdx.z * iters * 256;
  const int dbase = w * 64;  // PV output d-slice per wave

  // ---- one-time Q pin: LDS[row][P] holds Q[row][P ^ (row&7)] (16B blocks).
#pragma unroll
  for (int j = 0; j < 8; ++j) {
    const int row = (j & 3) * 8 + w;
    const unsigned short* src =
        ((j >> 2) ? Ql : Qh) + (size_t)(b * SEQ + q0 + row) * DIM + (lane ^ w) * 8;
    gload_lds16(src, &Qpin[j * 4096 + w * 512]);
  }
  __syncthreads();  // one-time: drains Q staging, all waves see full Qpin

  const unsigned short* kpl0 = Kh + (size_t)b * SEQ * DIM;
  const unsigned short* kpl1 = Kl + (size_t)b * SEQ * DIM;

  bf16x8 kb[4][2][2];  // [ring-slot][k-subtile][plane], statically indexed
  f32x4 Of[2][4] = {};
  float m_r[2][4], l_r[2][4];
#pragma unroll
  for (int qs = 0; qs < 2; ++qs)
#pragma unroll
    for (int r = 0; r < 4; ++r) { m_r[qs][r] = -3.0e38f; l_r[qs][r] = 0.0f; }

  // prologue: prefetch chunks 0,1,2
  LOADK(0, kbase, 0);
  LOADK(1, kbase, 1);
  LOADK(2, kbase, 2);

  for (int t = 0; t < iters; ++t) {
    const int k0 = kbase + t * 256;
    f32x4 sa[2][2] = {};  // [q-subtile][k-subtile]

    // ---- S = Q K^T over 16 chunks of 32 d: barrier-free, 4-deep reg ring ----
#pragma unroll
    for (int c = 0; c < 16; ++c) {
      // issue chunk c+3 (slot (c+3)&3); may belong to the next iteration
      {
        const int cc = (c + 3) & 15;        // compile-time
        const int dt = (c + 3) >> 4;        // 0 or 1, compile-time
        if (t + dt < iters) LOADK((c + 3) & 3, kbase + (t + dt) * 256, cc);
      }
      bf16x8 qfh[2], qfl[2];
#pragma unroll
      for (int qs = 0; qs < 2; ++qs) {
        const int row = qs * 16 + l15;
        const int off = row * 512 + ((c * 4 + quad) ^ (l15 & 7)) * 8;
        qfh[qs] = *(const bf16x8*)&Qpin[off];
        qfl[qs] = *(const bf16x8*)&Qpin[16384 + off];
      }
      __builtin_amdgcn_s_setprio(1);
#pragma unroll
      for (int qs = 0; qs < 2; ++qs)
#pragma unroll
        for (int s = 0; s < 2; ++s) {
          sa[qs][s] = __builtin_amdgcn_mfma_f32_16x16x32_bf16(
              qfh[qs], kb[c & 3][s][0], sa[qs][s], 0, 0, 0);
          sa[qs][s] = __builtin_amdgcn_mfma_f32_16x16x32_bf16(
              qfh[qs], kb[c & 3][s][1], sa[qs][s], 0, 0, 0);
          sa[qs][s] = __builtin_amdgcn_mfma_f32_16x16x32_bf16(
              qfl[qs], kb[c & 3][s][0], sa[qs][s], 0, 0, 0);
        }
      __builtin_amdgcn_s_setprio(0);
    }

    // ---- online softmax: wave owns all 32 rows for cols [w*32, w*32+32) ----
#pragma unroll
    for (int qs = 0; qs < 2; ++qs)
#pragma unroll
      for (int r = 0; r < 4; ++r) {
        float v = fmaxf(sa[qs][0][r], sa[qs][1][r]);
#pragma unroll
        for (int off = 1; off < 16; off <<= 1) v = fmaxf(v, __shfl_xor(v, off, 64));
        if (l15 == 0) red1[qs * 16 + quad * 4 + r][w] = v;
      }
    asm volatile("s_waitcnt lgkmcnt(0)" ::: "memory");
    __builtin_amdgcn_sched_barrier(0);
    __builtin_amdgcn_s_barrier();  // B1

    float al_r[2][4];
#pragma unroll
    for (int qs = 0; qs < 2; ++qs)
#pragma unroll
      for (int r = 0; r < 4; ++r) {
        const int row = qs * 16 + quad * 4 + r;
        f32x4 ra = *(const f32x4*)&red1[row][0];
        f32x4 rb = *(const f32x4*)&red1[row][4];
        float mx = fmaxf(fmaxf(fmaxf(ra[0], ra[1]), fmaxf(ra[2], ra[3])),
                         fmaxf(fmaxf(rb[0], rb[1]), fmaxf(rb[2], rb[3])));
        float mn = fmaxf(m_r[qs][r], mx);
        al_r[qs][r] = __expf(m_r[qs][r] - mn);
        m_r[qs][r] = mn;
        float p0 = __expf(sa[qs][0][r] - mn);
        float p1 = __expf(sa[qs][1][r] - mn);
        const int c0 = w * 32 + l15, c1 = c0 + 16;
        PsH[row * 256 + ((c0 >> 3) ^ row) * 8 + (c0 & 7)] = f2bf(p0);
        PsH[row * 256 + ((c1 >> 3) ^ row) * 8 + (c1 & 7)] = f2bf(p1);
        float sum = p0 + p1;
#pragma unroll
        for (int off = 1; off < 16; off <<= 1) sum += __shfl_xor(sum, off, 64);
        if (l15 == 0) red2[row][w] = sum;
      }
    asm volatile("s_waitcnt lgkmcnt(0)" ::: "memory");
    __builtin_amdgcn_sched_barrier(0);
    __builtin_amdgcn_s_barrier();  // B2

#pragma unroll
    for (int qs = 0; qs < 2; ++qs)
#pragma unroll
      for (int r = 0; r < 4; ++r) {
        const int row = qs * 16 + quad * 4 + r;
        f32x4 ra = *(const f32x4*)&red2[row][0];
        f32x4 rb = *(const f32x4*)&red2[row][4];
        l_r[qs][r] = l_r[qs][r] * al_r[qs][r] +
                     (ra[0] + ra[1] + ra[2] + ra[3] + rb[0] + rb[1] + rb[2] + rb[3]);
      }

    // ---- O = O*alpha + P @ x ; wave d-slice [dbase, dbase+64) ----
#pragma unroll
    for (int qt = 0; qt < 2; ++qt)
#pragma unroll
      for (int nt = 0; nt < 4; ++nt)
#pragma unroll
        for (int r = 0; r < 4; ++r) Of[qt][nt][r] *= al_r[qt][r];

    const unsigned short* Xb =
        Xth + ((size_t)(b * DIM + dbase) + l15) * SEQ + k0 + quad * 8;
    bf16x8 xfr[2][4];
#pragma unroll
    for (int i = 0; i < 4; ++i)
      xfr[0][i] = *(const bf16x8*)(Xb + (size_t)(i * 16) * SEQ);
#pragma unroll
    for (int ks = 0; ks < 8; ++ks) {
      if (ks < 7) {
#pragma unroll
        for (int i = 0; i < 4; ++i)
          xfr[(ks + 1) & 1][i] =
              *(const bf16x8*)(Xb + (size_t)(i * 16) * SEQ + (ks + 1) * 32);
      }
      bf16x8 Ph[2];
#pragma unroll
      for (int qt = 0; qt < 2; ++qt) {
        const int prow = qt * 16 + l15;
        const int phys = (ks * 4 + quad) ^ prow;
        Ph[qt] = *(const bf16x8*)&PsH[prow * 256 + phys * 8];
      }
      __builtin_amdgcn_s_setprio(1);
#pragma unroll
      for (int i = 0; i < 4; ++i)
#pragma unroll
        for (int qt = 0; qt < 2; ++qt)
          Of[qt][i] = __builtin_amdgcn_mfma_f32_16x16x32_bf16(
              Ph[qt], xfr[ks & 1][i], Of[qt][i], 0, 0, 0);
      __builtin_amdgcn_s_setprio(0);
    }
    // no barrier here: next iter's PsH/red writes are gated by B1/B2, which
    // every wave reaches only after finishing this PV (program order).
  }

  // ---- epilogue: each wave writes its own rows x d-slice; no LDS needed ----
  if (gridDim.z == 1) {
#pragma unroll
    for (int qt = 0; qt < 2; ++qt)
#pragma unroll
      for (int r = 0; r < 4; ++r) {
        const float inv = 1.0f / l_r[qt][r];
        const size_t ro =
            ((size_t)(b * SEQ + q0 + qt * 16 + quad * 4 + r)) * DIM + dbase;
#pragma unroll
        for (int i = 0; i < 4; ++i) out[ro + i * 16 + l15] = Of[qt][i][r] * inv;
      }
  } else {
    float* Ob = (blockIdx.z == 0) ? out : Opart;
#pragma unroll
    for (int qt = 0; qt < 2; ++qt)
#pragma unroll
      for (int r = 0; r < 4; ++r) {
        const size_t ro =
            ((size_t)(b * SEQ + q0 + qt * 16 + quad * 4 + r)) * DIM + dbase;
#pragma unroll
        for (int i = 0; i < 4; ++i) Ob[ro + i * 16 + l15] = Of[qt][i][r];
      }
    if (w == 0 && l15 == 0) {
      size_t ri = (size_t)blockIdx.z * (BATCH * SEQ) + (size_t)b * SEQ + q0;
#pragma unroll
      for (int qs = 0; qs < 2; ++qs)
#pragma unroll
        for (int r = 0; r < 4; ++r) {
          Mp[ri + qs * 16 + quad * 4 + r] = m_r[qs][r];
          Lp[ri + qs * 16 + quad * 4 + r] = l_r[qs][r];
        }
    }
  }
}

// ---------------------------------------------------------------------------
// Merge split-K partials: z=0 partial lives in `out`, z=1 in Opart.
// ---------------------------------------------------------------------------
__global__ __launch_bounds__(256) void merge_kernel(
    float* __restrict__ out, const float* __restrict__ Op,
    const float* __restrict__ Mp, const float* __restrict__ Lp) {
  const int NR = BATCH * SEQ;
  size_t e = ((size_t)blockIdx.x * 256 + threadIdx.x) * 4;
  int row = (int)(e >> 9);
  float m0 = Mp[row], m1 = Mp[NR + row];
  float l0 = Lp[row], l1 = Lp[NR + row];
  float m = fmaxf(m0, m1);
  float a0 = __expf(m0 - m), a1 = __expf(m1 - m);
  float inv = 1.0f / (a0 * l0 + a1 * l1);
  float4 o0 = *(const float4*)(out + e);
  float4 o1 = *(const float4*)(Op + e);
  float4 r;
  r.x = (a0 * o0.x + a1 * o1.x) * inv;
  r.y = (a0 * o0.y + a1 * o1.y) * inv;
  r.z = (a0 * o0.z + a1 * o1.z) * inv;
  r.w = (a0 * o0.w + a1 * o1.w) * inv;
  *(float4*)(out + e) = r;
}

// ---------------------------------------------------------------------------
extern "C" void kernel_launch(void* const* d_in, const int* in_sizes, int n_in,
                              void* d_out, int out_size, void* d_ws,
                              size_t ws_size, hipStream_t stream) {
  const float* x   = (const float*)d_in[0];
  const float* rot = (const float*)d_in[1];
  const float* ent = (const float*)d_in[2];
  float* out = (float*)d_out;

  const size_t NE = (size_t)BATCH * SEQ * DIM;  // 16,777,216
  unsigned short* qh  = (unsigned short*)d_ws;
  unsigned short* ql  = qh + NE;
  unsigned short* kh  = ql + NE;
  unsigned short* kl  = kh + NE;
  unsigned short* xth = kl + NE;
  unsigned short* xh  = xth + NE;
  unsigned short* xl  = xh + NE;
  unsigned short* wrh = xl + NE;
  unsigned short* wrl = wrh + 262144;
  unsigned short* weh = wrl + 262144;
  unsigned short* wel = weh + 262144;
  float* Opart = (float*)(wel + 262144);  // NE floats (z=1 partial)
  float* Mp    = Opart + NE;              // 2 * 32768
  float* Lp    = Mp + 2 * (BATCH * SEQ);

  const size_t need2 =
      (7 * NE + 4 * 262144) * sizeof(unsigned short) +
      (NE + 4 * (size_t)(BATCH * SEQ)) * sizeof(float);
  const int splits = (ws_size >= need2) ? 2 : 1;

  wt_split_kernel<<<128, 256, 0, stream>>>(rot, ent, wrh, wrl, weh, wel);
  xt_split_kernel<<<dim3(SEQ / 64, DIM / 64, BATCH), 256, 0, stream>>>(x, xth, xh, xl);
  proj_both<<<dim3(BATCH * SEQ / 64, DIM / 64), 256, 0, stream>>>(
      xh, xl, wrh, wrl, weh, wel, qh, ql, kh, kl);

  attn_mfma<<<dim3(BATCH, SEQ / 32, splits), 512, 0, stream>>>(
      qh, ql, kh, kl, xth, out, Opart, Mp, Lp);
  if (splits == 2) {
    merge_kernel<<<(unsigned)(NE / 1024), 256, 0, stream>>>(out, Opart, Mp, Lp);
  }
}